// Round 3
// baseline (1577.641 us; speedup 1.0000x reference)
//
#include <hip/hip_runtime.h>
#include <hip/hip_bf16.h>

#define NNODES 100000
#define NEDGES 1600000
#define INF_   128
#define HF     128
#define OUTF   112
#define NLAYERS 4
#define NNETS  3

typedef __attribute__((ext_vector_type(8))) short bf16x8;
typedef __attribute__((ext_vector_type(8))) unsigned short u16x8;
typedef __attribute__((ext_vector_type(4))) float f32x4;

__device__ __forceinline__ float bf2f(short u){
  unsigned x = ((unsigned)(unsigned short)u) << 16;
  return __builtin_bit_cast(float, x);
}
__device__ __forceinline__ unsigned short f2bf(float f){
  unsigned u = __builtin_bit_cast(unsigned, f);
  u += 0x7fffu + ((u >> 16) & 1u);   // RNE
  return (unsigned short)(u >> 16);
}

// ---------------- int64-vs-int32 edge_index format probe ----------------
// int64 data: values < 2^31 -> every high word is 0. int32 data: "high words"
// are random node ids -> essentially never all zero. flag=1 means int64.
__global__ void detect_fmt(const unsigned long long* __restrict__ ei64, int* __restrict__ flag){
  unsigned long long v = ei64[threadIdx.x];          // 64 threads, 512B read: in bounds either way
  unsigned long long b = __ballot((v >> 32) != 0ull);
  if (threadIdx.x == 0) flag[0] = (b == 0ull) ? 1 : 0;
}

__device__ __forceinline__ int load_dst(const int* ei, int is64, int e){
  return is64 ? ei[2*(NEDGES + e)] : ei[NEDGES + e];
}
__device__ __forceinline__ int load_src(const int* ei, int is64, int e){
  return is64 ? ei[2*e] : ei[e];
}

// ---------------- CSR build ----------------
__global__ void zero_counts(int* counts){
  int i = blockIdx.x*256 + threadIdx.x;
  if (i < NNODES) counts[i] = 0;
}

__global__ void hist_kernel(const int* __restrict__ ei, const int* __restrict__ flag, int* counts){
  int e = blockIdx.x*256 + threadIdx.x;
  if (e < NEDGES){
    int d = load_dst(ei, flag[0], e);
    if ((unsigned)d < NNODES) atomicAdd(&counts[d], 1);
  }
}

__global__ __launch_bounds__(256) void scan1(const int* __restrict__ counts,
                                             int* __restrict__ scanned,
                                             int* __restrict__ partials){
  __shared__ int s[256];
  int t = threadIdx.x, i = blockIdx.x*256 + t;
  int v = (i < NNODES) ? counts[i] : 0;
  s[t] = v; __syncthreads();
  for (int off=1; off<256; off<<=1){
    int a = (t >= off) ? s[t-off] : 0;
    __syncthreads();
    s[t] += a;
    __syncthreads();
  }
  if (i < NNODES) scanned[i] = s[t] - v;    // exclusive within block
  if (t == 255) partials[blockIdx.x] = s[255];
}

__global__ __launch_bounds__(512) void scan2(int* partials, int G){
  __shared__ int s[512];
  int t = threadIdx.x;
  int v = (t < G) ? partials[t] : 0;
  s[t] = v; __syncthreads();
  for (int off=1; off<512; off<<=1){
    int a = (t >= off) ? s[t-off] : 0;
    __syncthreads();
    s[t] += a;
    __syncthreads();
  }
  if (t < G) partials[t] = s[t] - v;        // exclusive block offsets
}

__global__ void scan3(const int* __restrict__ scanned, const int* __restrict__ partials,
                      int* __restrict__ row_ptr, int* __restrict__ cursor){
  int i = blockIdx.x*256 + threadIdx.x;
  if (i < NNODES){
    int v = scanned[i] + partials[i>>8];
    row_ptr[i] = v;
    cursor[i]  = v;
  } else if (i == NNODES){
    row_ptr[NNODES] = NEDGES;
  }
}

__global__ void scatter_kernel(const int* __restrict__ ei, const float* __restrict__ ew,
                               const int* __restrict__ flag,
                               int* cursor, int* __restrict__ csr_src, float* __restrict__ csr_w){
  int e = blockIdx.x*256 + threadIdx.x;
  if (e < NEDGES){
    int is64 = flag[0];
    int s = load_src(ei, is64, e);
    int d = load_dst(ei, is64, e);
    if ((unsigned)d < NNODES && (unsigned)s < NNODES){
      int pos = atomicAdd(&cursor[d], 1);
      if ((unsigned)pos < NEDGES){
        csr_src[pos] = s;
        csr_w[pos]   = ew[e];
      }
    }
  }
}

// ---------------- weight prep (fp32 -> bf16, transposed to [C][K]) ----------------
__global__ void prep_w(const float* __restrict__ w0, const float* __restrict__ cw,
                       const float* __restrict__ w1,
                       short* __restrict__ w0t, short* __restrict__ cwt, short* __restrict__ w1t){
  int i = blockIdx.x*256 + threadIdx.x;
  const int n0 = NNETS*HF*HF;
  const int n1 = NNETS*NLAYERS*HF*HF;
  const int n2 = NNETS*OUTF*HF;
  if (i < n0){
    int net = i/(HF*HF), r = i%(HF*HF), c = r/HF, k = r%HF;
    w0t[i] = (short)f2bf(w0[(size_t)net*HF*HF + k*HF + c]);
  } else if (i < n0 + n1){
    int j = i - n0;
    int nl = j/(HF*HF), r = j%(HF*HF), c = r/HF, k = r%HF;
    cwt[j] = (short)f2bf(cw[(size_t)nl*HF*HF + k*HF + c]);
  } else if (i < n0 + n1 + n2){
    int j = i - n0 - n1;
    int net = j/(OUTF*HF), r = j%(OUTF*HF), c = r/HF, k = r%HF;
    w1t[j] = (short)f2bf(w1[(size_t)net*HF*OUTF + k*OUTF + c]);
  }
}

// ---------------- GEMM: [M x 128] @ [128 x C] bf16 MFMA (+fused epilogue) ----------------
// A staged in LDS (32 KB). B fragments read directly from global (Wt is 32 KB,
// L1/L2-resident, reused by all blocks) -> total static LDS 32 KB.
// MODE 0: A = fp32 Af; out = relu(acc + bias) -> outb (h) and outb2 (x0), bf16
// MODE 1: A = bf16 t;  out = relu((1-beta)*t + beta*acc) -> outb (h), bf16
// MODE 2: A = bf16 h;  logits = acc + bias; fused log_softmax; ensemble-accumulate into outf
//         net_phase 0: write, 1: add, 2: add then *1/3
template<int C, int MODE>
__global__ __launch_bounds__(256) void gemm128(
    const float* __restrict__ Af, const short* __restrict__ A,
    const short* __restrict__ Wt, const float* __restrict__ bias,
    short* __restrict__ outb, short* __restrict__ outb2, float* __restrict__ outf,
    float beta, int net_phase, int M)
{
  __shared__ short As[128*128];
  const int t = threadIdx.x;
  const int rowBase = blockIdx.x * 128;
  constexpr int NT = C/16;

  // stage A tile (128 rows x 128 k), XOR-swizzled on k-bits[3:5]
  #pragma unroll
  for (int it=0; it<8; ++it){
    int r = it*16 + (t>>4);
    int k = (t&15)*8;
    int gr = rowBase + r;
    bf16x8 v = {0,0,0,0,0,0,0,0};
    if (gr < M){
      if (MODE == 0){
        float4 f0 = *(const float4*)&Af[(size_t)gr*128 + k];
        float4 f1 = *(const float4*)&Af[(size_t)gr*128 + k + 4];
        v[0]=(short)f2bf(f0.x); v[1]=(short)f2bf(f0.y); v[2]=(short)f2bf(f0.z); v[3]=(short)f2bf(f0.w);
        v[4]=(short)f2bf(f1.x); v[5]=(short)f2bf(f1.y); v[6]=(short)f2bf(f1.z); v[7]=(short)f2bf(f1.w);
      } else {
        v = *(const bf16x8*)&A[(size_t)gr*128 + k];
      }
    }
    *(bf16x8*)&As[r*128 + (k ^ ((r&7)<<3))] = v;
  }
  __syncthreads();

  const int wid = t>>6, lane = t&63;
  const int l16 = lane&15, kg = lane>>4;
  f32x4 acc[2][NT];
  #pragma unroll
  for (int mt=0; mt<2; ++mt)
    #pragma unroll
    for (int nt=0; nt<NT; ++nt){ acc[mt][nt][0]=0.f; acc[mt][nt][1]=0.f; acc[mt][nt][2]=0.f; acc[mt][nt][3]=0.f; }

  #pragma unroll
  for (int ks=0; ks<4; ++ks){
    int k0 = ks*32 + kg*8;
    bf16x8 a0, a1;
    { int r = wid*32 + l16;      a0 = *(const bf16x8*)&As[r*128 + (k0 ^ ((r&7)<<3))]; }
    { int r = wid*32 + 16 + l16; a1 = *(const bf16x8*)&As[r*128 + (k0 ^ ((r&7)<<3))]; }
    #pragma unroll
    for (int nt=0; nt<NT; ++nt){
      bf16x8 b = *(const bf16x8*)&Wt[(size_t)(nt*16 + l16)*128 + k0];
      acc[0][nt] = __builtin_amdgcn_mfma_f32_16x16x32_bf16(a0, b, acc[0][nt], 0, 0, 0);
      acc[1][nt] = __builtin_amdgcn_mfma_f32_16x16x32_bf16(a1, b, acc[1][nt], 0, 0, 0);
    }
  }

  if (MODE == 2){
    #pragma unroll
    for (int mt=0; mt<2; ++mt)
      #pragma unroll
      for (int nt=0; nt<NT; ++nt){
        float b = bias[nt*16 + l16];
        #pragma unroll
        for (int j=0; j<4; ++j) acc[mt][nt][j] += b;
      }
    #pragma unroll
    for (int mt=0; mt<2; ++mt){
      #pragma unroll
      for (int j=0; j<4; ++j){
        float m = -3.4e38f;
        #pragma unroll
        for (int nt=0; nt<NT; ++nt) m = fmaxf(m, acc[mt][nt][j]);
        #pragma unroll
        for (int k=1; k<16; k<<=1) m = fmaxf(m, __shfl_xor(m, k));
        float e = 0.f;
        #pragma unroll
        for (int nt=0; nt<NT; ++nt) e += expf(acc[mt][nt][j] - m);
        #pragma unroll
        for (int k=1; k<16; k<<=1) e += __shfl_xor(e, k);
        float lse = m + logf(e);
        int row = rowBase + wid*32 + mt*16 + kg*4 + j;
        if (row < M){
          #pragma unroll
          for (int nt=0; nt<NT; ++nt){
            size_t oi = (size_t)row*OUTF + nt*16 + l16;
            float v = acc[mt][nt][j] - lse;
            if (net_phase == 0)      outf[oi] = v;
            else if (net_phase == 2) outf[oi] = (outf[oi] + v) * (1.f/3.f);
            else                     outf[oi] += v;
          }
        }
      }
    }
  } else {
    #pragma unroll
    for (int mt=0; mt<2; ++mt){
      #pragma unroll
      for (int nt=0; nt<NT; ++nt){
        #pragma unroll
        for (int j=0; j<4; ++j){
          int rl  = wid*32 + mt*16 + kg*4 + j;
          int row = rowBase + rl;
          int col = nt*16 + l16;
          if (row < M){
            float v = acc[mt][nt][j];
            if (MODE == 0){
              v += bias[col];
              v = fmaxf(v, 0.f);
              short bv = (short)f2bf(v);
              outb [(size_t)row*128 + col] = bv;
              outb2[(size_t)row*128 + col] = bv;
            } else {
              float av = bf2f(As[rl*128 + (col ^ ((rl&7)<<3))]);
              v = fmaxf((1.f-beta)*av + beta*v, 0.f);
              outb[(size_t)row*128 + col] = (short)f2bf(v);
            }
          }
        }
      }
    }
  }
}

// ---------------- SpMM: t = 0.9 * (A @ h) + 0.1 * x0 ----------------
// one wave per node; quarter-wave per edge (4 edges in flight); 16 lanes x 16B per gather
__global__ __launch_bounds__(256) void spmm(
    const int* __restrict__ row_ptr, const int* __restrict__ csr_src,
    const float* __restrict__ csr_w,
    const short* __restrict__ h, const short* __restrict__ x0,
    short* __restrict__ tout)
{
  int node = blockIdx.x*4 + (threadIdx.x>>6);
  int lane = threadIdx.x & 63;
  int q    = lane >> 4;
  int f8   = (lane & 15) * 8;
  int start = row_ptr[node], end = row_ptr[node+1];
  float acc[8] = {0.f,0.f,0.f,0.f,0.f,0.f,0.f,0.f};
  for (int e = start + q; e < end; e += 4){
    int s   = csr_src[e];
    float w = csr_w[e];
    bf16x8 v = *(const bf16x8*)&h[(size_t)s*128 + f8];
    #pragma unroll
    for (int j=0;j<8;++j) acc[j] += w * bf2f(v[j]);
  }
  #pragma unroll
  for (int j=0;j<8;++j){
    acc[j] += __shfl_xor(acc[j], 16);
    acc[j] += __shfl_xor(acc[j], 32);
  }
  if (q == 0){
    size_t base = (size_t)node*128 + f8;
    bf16x8 xv = *(const bf16x8*)&x0[base];
    u16x8 o;
    #pragma unroll
    for (int j=0;j<8;++j) o[j] = f2bf(0.9f*acc[j] + 0.1f*bf2f(xv[j]));
    *(u16x8*)&tout[base] = o;
  }
}

extern "C" void kernel_launch(void* const* d_in, const int* in_sizes, int n_in,
                              void* d_out, int out_size, void* d_ws, size_t ws_size,
                              hipStream_t stream){
  const float* x  = (const float*)d_in[0];
  const int*   ei = (const int*)d_in[1];   // int32 or int64 storage — probed on device
  const float* ew = (const float*)d_in[2];
  const float* w0 = (const float*)d_in[3];
  const float* b0 = (const float*)d_in[4];
  const float* w1 = (const float*)d_in[5];
  const float* b1 = (const float*)d_in[6];
  const float* cw = (const float*)d_in[7];
  float* out = (float*)d_out;

  char* ws = (char*)d_ws;
  size_t o = 0;
  auto alloc = [&](size_t b){ size_t r = o; o += (b + 255) & ~(size_t)255; return r; };
  int*   flag     = (int*)(ws + alloc(256));
  int*   counts   = (int*)(ws + alloc((size_t)NNODES*4));
  int*   scanned  = (int*)(ws + alloc((size_t)NNODES*4));
  int*   cursor   = (int*)(ws + alloc((size_t)NNODES*4));
  int*   row_ptr  = (int*)(ws + alloc((size_t)(NNODES+1)*4));
  int*   partials = (int*)(ws + alloc(512*4));
  int*   csr_src  = (int*)(ws + alloc((size_t)NEDGES*4));
  float* csr_w    = (float*)(ws + alloc((size_t)NEDGES*4));
  short* w0t = (short*)(ws + alloc((size_t)NNETS*HF*HF*2));
  short* cwt = (short*)(ws + alloc((size_t)NNETS*NLAYERS*HF*HF*2));
  short* w1t = (short*)(ws + alloc((size_t)NNETS*OUTF*HF*2));
  short* hbuf= (short*)(ws + alloc((size_t)NNODES*HF*2));
  short* x0b = (short*)(ws + alloc((size_t)NNODES*HF*2));
  short* tb  = (short*)(ws + alloc((size_t)NNODES*HF*2));
  (void)ws_size; (void)in_sizes; (void)n_in; (void)out_size;
  // total ws use ~92 MB

  // CSR build (by dst), rebuilt every call (deterministic work)
  detect_fmt    <<<1,   64,  0, stream>>>((const unsigned long long*)ei, flag);
  zero_counts   <<<391, 256, 0, stream>>>(counts);
  hist_kernel   <<<6250,256, 0, stream>>>(ei, flag, counts);
  scan1         <<<391, 256, 0, stream>>>(counts, scanned, partials);
  scan2         <<<1,   512, 0, stream>>>(partials, 391);
  scan3         <<<391, 256, 0, stream>>>(scanned, partials, row_ptr, cursor);
  scatter_kernel<<<6250,256, 0, stream>>>(ei, ew, flag, cursor, csr_src, csr_w);

  prep_w<<<1128, 256, 0, stream>>>(w0, cw, w1, w0t, cwt, w1t);

  for (int net = 0; net < NNETS; ++net){
    const short* w0n = w0t + (size_t)net*HF*HF;
    const short* w1n = w1t + (size_t)net*OUTF*HF;
    const float* b0n = b0 + (size_t)net*HF;
    const float* b1n = b1 + (size_t)net*OUTF;

    // h0 = relu(x @ w0 + b0); x0 = h0
    gemm128<128,0><<<782, 256, 0, stream>>>(x, nullptr, w0n, b0n,
                                            hbuf, x0b, nullptr, 0.f, 0, NNODES);
    for (int l=0; l<NLAYERS; ++l){
      float beta = logf(0.5f/(float)(l+1) + 1.0f);
      const short* cwn = cwt + ((size_t)net*NLAYERS + l)*HF*HF;
      spmm<<<25000, 256, 0, stream>>>(row_ptr, csr_src, csr_w, hbuf, x0b, tb);
      gemm128<128,1><<<782, 256, 0, stream>>>(nullptr, tb, cwn, nullptr,
                                              hbuf, nullptr, nullptr, beta, 0, NNODES);
    }
    // logits = h @ w1 + b1 ; fused log_softmax ; ensemble-mean accumulate in d_out
    gemm128<112,2><<<782, 256, 0, stream>>>(nullptr, hbuf, w1n, b1n,
                                            nullptr, nullptr, out, 0.f, net, NNODES);
  }
}

// Round 4
// 1502.642 us; speedup vs baseline: 1.0499x; 1.0499x over previous
//
#include <hip/hip_runtime.h>
#include <hip/hip_bf16.h>

#define NNODES 100000
#define NEDGES 1600000
#define INF_   128
#define HF     128
#define OUTF   112
#define NLAYERS 4
#define NNETS  3

typedef __attribute__((ext_vector_type(8))) short bf16x8;
typedef __attribute__((ext_vector_type(8))) unsigned short u16x8;
typedef __attribute__((ext_vector_type(4))) float f32x4;
typedef unsigned long long u64;

__device__ __forceinline__ float bf2f(short u){
  unsigned x = ((unsigned)(unsigned short)u) << 16;
  return __builtin_bit_cast(float, x);
}
__device__ __forceinline__ unsigned short f2bf(float f){
  unsigned u = __builtin_bit_cast(unsigned, f);
  u += 0x7fffu + ((u >> 16) & 1u);   // RNE
  return (unsigned short)(u >> 16);
}

// ---------------- int64-vs-int32 edge_index format probe ----------------
__global__ void detect_fmt(const u64* __restrict__ ei64, int* __restrict__ flag){
  u64 v = ei64[threadIdx.x];
  u64 b = __ballot((v >> 32) != 0ull);
  if (threadIdx.x == 0) flag[0] = (b == 0ull) ? 1 : 0;
}

__device__ __forceinline__ int load_dst(const int* ei, int is64, int e){
  return is64 ? ei[2*(NEDGES + e)] : ei[NEDGES + e];
}
__device__ __forceinline__ int load_src(const int* ei, int is64, int e){
  return is64 ? ei[2*e] : ei[e];
}

// ---------------- CSR build ----------------
__global__ void zero_counts(int* counts){
  int i = blockIdx.x*256 + threadIdx.x;
  if (i < NNODES) counts[i] = 0;
}

__global__ void hist_kernel(const int* __restrict__ ei, const int* __restrict__ flag, int* counts){
  int e = blockIdx.x*256 + threadIdx.x;
  if (e < NEDGES){
    int d = load_dst(ei, flag[0], e);
    if ((unsigned)d < NNODES) atomicAdd(&counts[d], 1);
  }
}

__global__ __launch_bounds__(256) void scan1(const int* __restrict__ counts,
                                             int* __restrict__ scanned,
                                             int* __restrict__ partials){
  __shared__ int s[256];
  int t = threadIdx.x, i = blockIdx.x*256 + t;
  int v = (i < NNODES) ? counts[i] : 0;
  s[t] = v; __syncthreads();
  for (int off=1; off<256; off<<=1){
    int a = (t >= off) ? s[t-off] : 0;
    __syncthreads();
    s[t] += a;
    __syncthreads();
  }
  if (i < NNODES) scanned[i] = s[t] - v;
  if (t == 255) partials[blockIdx.x] = s[255];
}

__global__ __launch_bounds__(512) void scan2(int* partials, int G){
  __shared__ int s[512];
  int t = threadIdx.x;
  int v = (t < G) ? partials[t] : 0;
  s[t] = v; __syncthreads();
  for (int off=1; off<512; off<<=1){
    int a = (t >= off) ? s[t-off] : 0;
    __syncthreads();
    s[t] += a;
    __syncthreads();
  }
  if (t < G) partials[t] = s[t] - v;
}

__global__ void scan3(const int* __restrict__ scanned, const int* __restrict__ partials,
                      int* __restrict__ row_ptr, int* __restrict__ cursor){
  int i = blockIdx.x*256 + threadIdx.x;
  if (i < NNODES){
    int v = scanned[i] + partials[i>>8];
    row_ptr[i] = v;
    cursor[i]  = v;
  } else if (i == NNODES){
    row_ptr[NNODES] = NEDGES;
  }
}

// packed CSR record: low 32 = src, high 32 = weight bits (single 8B scattered write)
__global__ void scatter_kernel(const int* __restrict__ ei, const float* __restrict__ ew,
                               const int* __restrict__ flag,
                               int* cursor, u64* __restrict__ csr_pack){
  int e = blockIdx.x*256 + threadIdx.x;
  if (e < NEDGES){
    int is64 = flag[0];
    int s = load_src(ei, is64, e);
    int d = load_dst(ei, is64, e);
    if ((unsigned)d < NNODES && (unsigned)s < NNODES){
      int pos = atomicAdd(&cursor[d], 1);
      if ((unsigned)pos < NEDGES){
        u64 pk = ((u64)__builtin_bit_cast(unsigned, ew[e]) << 32) | (unsigned)s;
        csr_pack[pos] = pk;
      }
    }
  }
}

// ---------------- weight prep (fp32 -> bf16, transposed to [C][K]) ----------------
__global__ void prep_w(const float* __restrict__ w0, const float* __restrict__ cw,
                       const float* __restrict__ w1,
                       short* __restrict__ w0t, short* __restrict__ cwt, short* __restrict__ w1t){
  int i = blockIdx.x*256 + threadIdx.x;
  const int n0 = NNETS*HF*HF;
  const int n1 = NNETS*NLAYERS*HF*HF;
  const int n2 = NNETS*OUTF*HF;
  if (i < n0){
    int net = i/(HF*HF), r = i%(HF*HF), c = r/HF, k = r%HF;
    w0t[i] = (short)f2bf(w0[(size_t)net*HF*HF + k*HF + c]);
  } else if (i < n0 + n1){
    int j = i - n0;
    int nl = j/(HF*HF), r = j%(HF*HF), c = r/HF, k = r%HF;
    cwt[j] = (short)f2bf(cw[(size_t)nl*HF*HF + k*HF + c]);
  } else if (i < n0 + n1 + n2){
    int j = i - n0 - n1;
    int net = j/(OUTF*HF), r = j%(OUTF*HF), c = r/HF, k = r%HF;
    w1t[j] = (short)f2bf(w1[(size_t)net*HF*OUTF + k*OUTF + c]);
  }
}

// ---------------- GEMM: [M x 128] @ [128 x C] bf16 MFMA (+fused epilogue) ----------------
template<int C, int MODE>
__global__ __launch_bounds__(256) void gemm128(
    const float* __restrict__ Af, const short* __restrict__ A,
    const short* __restrict__ Wt, const float* __restrict__ bias,
    short* __restrict__ outb, short* __restrict__ outb2, float* __restrict__ outf,
    float beta, int net_phase, int M)
{
  __shared__ short As[128*128];
  const int t = threadIdx.x;
  const int rowBase = blockIdx.x * 128;
  constexpr int NT = C/16;

  #pragma unroll
  for (int it=0; it<8; ++it){
    int r = it*16 + (t>>4);
    int k = (t&15)*8;
    int gr = rowBase + r;
    bf16x8 v = {0,0,0,0,0,0,0,0};
    if (gr < M){
      if (MODE == 0){
        float4 f0 = *(const float4*)&Af[(size_t)gr*128 + k];
        float4 f1 = *(const float4*)&Af[(size_t)gr*128 + k + 4];
        v[0]=(short)f2bf(f0.x); v[1]=(short)f2bf(f0.y); v[2]=(short)f2bf(f0.z); v[3]=(short)f2bf(f0.w);
        v[4]=(short)f2bf(f1.x); v[5]=(short)f2bf(f1.y); v[6]=(short)f2bf(f1.z); v[7]=(short)f2bf(f1.w);
      } else {
        v = *(const bf16x8*)&A[(size_t)gr*128 + k];
      }
    }
    *(bf16x8*)&As[r*128 + (k ^ ((r&7)<<3))] = v;
  }
  __syncthreads();

  const int wid = t>>6, lane = t&63;
  const int l16 = lane&15, kg = lane>>4;
  f32x4 acc[2][NT];
  #pragma unroll
  for (int mt=0; mt<2; ++mt)
    #pragma unroll
    for (int nt=0; nt<NT; ++nt){ acc[mt][nt][0]=0.f; acc[mt][nt][1]=0.f; acc[mt][nt][2]=0.f; acc[mt][nt][3]=0.f; }

  #pragma unroll
  for (int ks=0; ks<4; ++ks){
    int k0 = ks*32 + kg*8;
    bf16x8 a0, a1;
    { int r = wid*32 + l16;      a0 = *(const bf16x8*)&As[r*128 + (k0 ^ ((r&7)<<3))]; }
    { int r = wid*32 + 16 + l16; a1 = *(const bf16x8*)&As[r*128 + (k0 ^ ((r&7)<<3))]; }
    #pragma unroll
    for (int nt=0; nt<NT; ++nt){
      bf16x8 b = *(const bf16x8*)&Wt[(size_t)(nt*16 + l16)*128 + k0];
      acc[0][nt] = __builtin_amdgcn_mfma_f32_16x16x32_bf16(a0, b, acc[0][nt], 0, 0, 0);
      acc[1][nt] = __builtin_amdgcn_mfma_f32_16x16x32_bf16(a1, b, acc[1][nt], 0, 0, 0);
    }
  }

  if (MODE == 2){
    #pragma unroll
    for (int mt=0; mt<2; ++mt)
      #pragma unroll
      for (int nt=0; nt<NT; ++nt){
        float b = bias[nt*16 + l16];
        #pragma unroll
        for (int j=0; j<4; ++j) acc[mt][nt][j] += b;
      }
    #pragma unroll
    for (int mt=0; mt<2; ++mt){
      #pragma unroll
      for (int j=0; j<4; ++j){
        float m = -3.4e38f;
        #pragma unroll
        for (int nt=0; nt<NT; ++nt) m = fmaxf(m, acc[mt][nt][j]);
        #pragma unroll
        for (int k=1; k<16; k<<=1) m = fmaxf(m, __shfl_xor(m, k));
        float e = 0.f;
        #pragma unroll
        for (int nt=0; nt<NT; ++nt) e += expf(acc[mt][nt][j] - m);
        #pragma unroll
        for (int k=1; k<16; k<<=1) e += __shfl_xor(e, k);
        float lse = m + logf(e);
        int row = rowBase + wid*32 + mt*16 + kg*4 + j;
        if (row < M){
          #pragma unroll
          for (int nt=0; nt<NT; ++nt){
            size_t oi = (size_t)row*OUTF + nt*16 + l16;
            float v = acc[mt][nt][j] - lse;
            if (net_phase == 0)      outf[oi] = v;
            else if (net_phase == 2) outf[oi] = (outf[oi] + v) * (1.f/3.f);
            else                     outf[oi] += v;
          }
        }
      }
    }
  } else {
    #pragma unroll
    for (int mt=0; mt<2; ++mt){
      #pragma unroll
      for (int nt=0; nt<NT; ++nt){
        #pragma unroll
        for (int j=0; j<4; ++j){
          int rl  = wid*32 + mt*16 + kg*4 + j;
          int row = rowBase + rl;
          int col = nt*16 + l16;
          if (row < M){
            float v = acc[mt][nt][j];
            if (MODE == 0){
              v += bias[col];
              v = fmaxf(v, 0.f);
              short bv = (short)f2bf(v);
              outb [(size_t)row*128 + col] = bv;
              outb2[(size_t)row*128 + col] = bv;
            } else {
              float av = bf2f(As[rl*128 + (col ^ ((rl&7)<<3))]);
              v = fmaxf((1.f-beta)*av + beta*v, 0.f);
              outb[(size_t)row*128 + col] = (short)f2bf(v);
            }
          }
        }
      }
    }
  }
}

// ---------------- SpMM: t = 0.9 * (A @ h) + 0.1 * x0 ----------------
// one wave per node; quarter-wave per edge; unroll x2 -> 8 gathers in flight/wave
__global__ __launch_bounds__(256) void spmm(
    const int* __restrict__ row_ptr, const u64* __restrict__ csr_pack,
    const short* __restrict__ h, const short* __restrict__ x0,
    short* __restrict__ tout)
{
  int node = blockIdx.x*4 + (threadIdx.x>>6);
  int lane = threadIdx.x & 63;
  int q    = lane >> 4;
  int f8   = (lane & 15) * 8;
  int start = row_ptr[node], end = row_ptr[node+1];
  float acc[8] = {0.f,0.f,0.f,0.f,0.f,0.f,0.f,0.f};
  int e = start + q;
  for (; e + 4 < end; e += 8){
    u64 p0 = csr_pack[e];
    u64 p1 = csr_pack[e+4];
    int   s0 = (int)(unsigned)p0;
    float w0 = __builtin_bit_cast(float, (unsigned)(p0 >> 32));
    int   s1 = (int)(unsigned)p1;
    float w1 = __builtin_bit_cast(float, (unsigned)(p1 >> 32));
    bf16x8 v0 = *(const bf16x8*)&h[(size_t)s0*128 + f8];
    bf16x8 v1 = *(const bf16x8*)&h[(size_t)s1*128 + f8];
    #pragma unroll
    for (int j=0;j<8;++j) acc[j] += w0 * bf2f(v0[j]) + w1 * bf2f(v1[j]);
  }
  if (e < end){
    u64 p0 = csr_pack[e];
    int   s0 = (int)(unsigned)p0;
    float w0 = __builtin_bit_cast(float, (unsigned)(p0 >> 32));
    bf16x8 v0 = *(const bf16x8*)&h[(size_t)s0*128 + f8];
    #pragma unroll
    for (int j=0;j<8;++j) acc[j] += w0 * bf2f(v0[j]);
  }
  #pragma unroll
  for (int j=0;j<8;++j){
    acc[j] += __shfl_xor(acc[j], 16);
    acc[j] += __shfl_xor(acc[j], 32);
  }
  if (q == 0){
    size_t base = (size_t)node*128 + f8;
    bf16x8 xv = *(const bf16x8*)&x0[base];
    u16x8 o;
    #pragma unroll
    for (int j=0;j<8;++j) o[j] = f2bf(0.9f*acc[j] + 0.1f*bf2f(xv[j]));
    *(u16x8*)&tout[base] = o;
  }
}

extern "C" void kernel_launch(void* const* d_in, const int* in_sizes, int n_in,
                              void* d_out, int out_size, void* d_ws, size_t ws_size,
                              hipStream_t stream){
  const float* x  = (const float*)d_in[0];
  const int*   ei = (const int*)d_in[1];
  const float* ew = (const float*)d_in[2];
  const float* w0 = (const float*)d_in[3];
  const float* b0 = (const float*)d_in[4];
  const float* w1 = (const float*)d_in[5];
  const float* b1 = (const float*)d_in[6];
  const float* cw = (const float*)d_in[7];
  float* out = (float*)d_out;

  char* ws = (char*)d_ws;
  size_t o = 0;
  auto alloc = [&](size_t b){ size_t r = o; o += (b + 255) & ~(size_t)255; return r; };
  int*   flag     = (int*)(ws + alloc(256));
  int*   counts   = (int*)(ws + alloc((size_t)NNODES*4));
  int*   scanned  = (int*)(ws + alloc((size_t)NNODES*4));
  int*   cursor   = (int*)(ws + alloc((size_t)NNODES*4));
  int*   row_ptr  = (int*)(ws + alloc((size_t)(NNODES+1)*4));
  int*   partials = (int*)(ws + alloc(512*4));
  u64*   csr_pack = (u64*)(ws + alloc((size_t)NEDGES*8));
  short* w0t = (short*)(ws + alloc((size_t)NNETS*HF*HF*2));
  short* cwt = (short*)(ws + alloc((size_t)NNETS*NLAYERS*HF*HF*2));
  short* w1t = (short*)(ws + alloc((size_t)NNETS*OUTF*HF*2));
  short* hbuf= (short*)(ws + alloc((size_t)NNODES*HF*2));
  short* x0b = (short*)(ws + alloc((size_t)NNODES*HF*2));
  short* tb  = (short*)(ws + alloc((size_t)NNODES*HF*2));
  (void)ws_size; (void)in_sizes; (void)n_in; (void)out_size;

  detect_fmt    <<<1,   64,  0, stream>>>((const u64*)ei, flag);
  zero_counts   <<<391, 256, 0, stream>>>(counts);
  hist_kernel   <<<6250,256, 0, stream>>>(ei, flag, counts);
  scan1         <<<391, 256, 0, stream>>>(counts, scanned, partials);
  scan2         <<<1,   512, 0, stream>>>(partials, 391);
  scan3         <<<391, 256, 0, stream>>>(scanned, partials, row_ptr, cursor);
  scatter_kernel<<<6250,256, 0, stream>>>(ei, ew, flag, cursor, csr_pack);

  prep_w<<<1128, 256, 0, stream>>>(w0, cw, w1, w0t, cwt, w1t);

  for (int net = 0; net < NNETS; ++net){
    const short* w0n = w0t + (size_t)net*HF*HF;
    const short* w1n = w1t + (size_t)net*OUTF*HF;
    const float* b0n = b0 + (size_t)net*HF;
    const float* b1n = b1 + (size_t)net*OUTF;

    gemm128<128,0><<<782, 256, 0, stream>>>(x, nullptr, w0n, b0n,
                                            hbuf, x0b, nullptr, 0.f, 0, NNODES);
    for (int l=0; l<NLAYERS; ++l){
      float beta = logf(0.5f/(float)(l+1) + 1.0f);
      const short* cwn = cwt + ((size_t)net*NLAYERS + l)*HF*HF;
      spmm<<<25000, 256, 0, stream>>>(row_ptr, csr_pack, hbuf, x0b, tb);
      gemm128<128,1><<<782, 256, 0, stream>>>(nullptr, tb, cwn, nullptr,
                                              hbuf, nullptr, nullptr, beta, 0, NNODES);
    }
    gemm128<112,2><<<782, 256, 0, stream>>>(nullptr, hbuf, w1n, b1n,
                                            nullptr, nullptr, out, 0.f, net, NNODES);
  }
}

// Round 5
// 1440.380 us; speedup vs baseline: 1.0953x; 1.0432x over previous
//
#include <hip/hip_runtime.h>
#include <hip/hip_bf16.h>

#define NNODES 100000
#define NEDGES 1600000
#define INF_   128
#define HF     128
#define OUTF   112
#define NLAYERS 4
#define NNETS  3

typedef __attribute__((ext_vector_type(8))) short bf16x8;
typedef __attribute__((ext_vector_type(8))) unsigned short u16x8;
typedef __attribute__((ext_vector_type(4))) float f32x4;
typedef unsigned long long u64;

__device__ __forceinline__ float bf2f(short u){
  unsigned x = ((unsigned)(unsigned short)u) << 16;
  return __builtin_bit_cast(float, x);
}
__device__ __forceinline__ unsigned short f2bf(float f){
  unsigned u = __builtin_bit_cast(unsigned, f);
  u += 0x7fffu + ((u >> 16) & 1u);   // RNE
  return (unsigned short)(u >> 16);
}

// ---------------- int64-vs-int32 edge_index format probe ----------------
__global__ void detect_fmt(const u64* __restrict__ ei64, int* __restrict__ flag){
  u64 v = ei64[threadIdx.x];
  u64 b = __ballot((v >> 32) != 0ull);
  if (threadIdx.x == 0) flag[0] = (b == 0ull) ? 1 : 0;
}

__device__ __forceinline__ int load_dst(const int* ei, int is64, int e){
  return is64 ? ei[2*(NEDGES + e)] : ei[NEDGES + e];
}
__device__ __forceinline__ int load_src(const int* ei, int is64, int e){
  return is64 ? ei[2*e] : ei[e];
}

// ---------------- CSR build ----------------
__global__ void zero_counts(int* counts){
  int i = blockIdx.x*256 + threadIdx.x;
  if (i < NNODES) counts[i] = 0;
}

__global__ void hist_kernel(const int* __restrict__ ei, const int* __restrict__ flag, int* counts){
  int e = blockIdx.x*256 + threadIdx.x;
  if (e < NEDGES){
    int d = load_dst(ei, flag[0], e);
    if ((unsigned)d < NNODES) atomicAdd(&counts[d], 1);
  }
}

__global__ __launch_bounds__(256) void scan1(const int* __restrict__ counts,
                                             int* __restrict__ scanned,
                                             int* __restrict__ partials){
  __shared__ int s[256];
  int t = threadIdx.x, i = blockIdx.x*256 + t;
  int v = (i < NNODES) ? counts[i] : 0;
  s[t] = v; __syncthreads();
  for (int off=1; off<256; off<<=1){
    int a = (t >= off) ? s[t-off] : 0;
    __syncthreads();
    s[t] += a;
    __syncthreads();
  }
  if (i < NNODES) scanned[i] = s[t] - v;
  if (t == 255) partials[blockIdx.x] = s[255];
}

__global__ __launch_bounds__(512) void scan2(int* partials, int G){
  __shared__ int s[512];
  int t = threadIdx.x;
  int v = (t < G) ? partials[t] : 0;
  s[t] = v; __syncthreads();
  for (int off=1; off<512; off<<=1){
    int a = (t >= off) ? s[t-off] : 0;
    __syncthreads();
    s[t] += a;
    __syncthreads();
  }
  if (t < G) partials[t] = s[t] - v;
}

__global__ void scan3(const int* __restrict__ scanned, const int* __restrict__ partials,
                      int* __restrict__ row_ptr, int* __restrict__ cursor){
  int i = blockIdx.x*256 + threadIdx.x;
  if (i < NNODES){
    int v = scanned[i] + partials[i>>8];
    row_ptr[i] = v;
    cursor[i]  = v;
  } else if (i == NNODES){
    row_ptr[NNODES] = NEDGES;
  }
}

__global__ void scatter_kernel(const int* __restrict__ ei, const float* __restrict__ ew,
                               const int* __restrict__ flag,
                               int* cursor, u64* __restrict__ csr_pack){
  int e = blockIdx.x*256 + threadIdx.x;
  if (e < NEDGES){
    int is64 = flag[0];
    int s = load_src(ei, is64, e);
    int d = load_dst(ei, is64, e);
    if ((unsigned)d < NNODES && (unsigned)s < NNODES){
      int pos = atomicAdd(&cursor[d], 1);
      if ((unsigned)pos < NEDGES){
        u64 pk = ((u64)__builtin_bit_cast(unsigned, ew[e]) << 32) | (unsigned)s;
        csr_pack[pos] = pk;
      }
    }
  }
}

// ---------------- weight prep (fp32 -> bf16, transposed to [C][K]) ----------------
__global__ void prep_w(const float* __restrict__ w0, const float* __restrict__ cw,
                       const float* __restrict__ w1,
                       short* __restrict__ w0t, short* __restrict__ cwt, short* __restrict__ w1t){
  int i = blockIdx.x*256 + threadIdx.x;
  const int n0 = NNETS*HF*HF;
  const int n1 = NNETS*NLAYERS*HF*HF;
  const int n2 = NNETS*OUTF*HF;
  if (i < n0){
    int net = i/(HF*HF), r = i%(HF*HF), c = r/HF, k = r%HF;
    w0t[i] = (short)f2bf(w0[(size_t)net*HF*HF + k*HF + c]);
  } else if (i < n0 + n1){
    int j = i - n0;
    int nl = j/(HF*HF), r = j%(HF*HF), c = r/HF, k = r%HF;
    cwt[j] = (short)f2bf(cw[(size_t)nl*HF*HF + k*HF + c]);
  } else if (i < n0 + n1 + n2){
    int j = i - n0 - n1;
    int net = j/(OUTF*HF), r = j%(OUTF*HF), c = r/HF, k = r%HF;
    w1t[j] = (short)f2bf(w1[(size_t)net*HF*OUTF + k*OUTF + c]);
  }
}

// All node-state buffers are interleaved: [node][net][128] bf16.
#define IDX(row,net) (((size_t)(row)*NNETS + (net))*128)

// ---------------- input GEMM: h0 = relu(x @ w0 + b0), x0 = h0, all 3 nets ----------------
__global__ __launch_bounds__(256) void gemm_in(
    const float* __restrict__ x, const short* __restrict__ w0t, const float* __restrict__ b0,
    short* __restrict__ h, short* __restrict__ x0)
{
  __shared__ short As[128*128];
  const int t = threadIdx.x;
  const int rowBase = blockIdx.x * 128;
  #pragma unroll
  for (int it=0; it<8; ++it){
    int r = it*16 + (t>>4);
    int k = (t&15)*8;
    int gr = rowBase + r;
    bf16x8 v = {0,0,0,0,0,0,0,0};
    if (gr < NNODES){
      float4 f0 = *(const float4*)&x[(size_t)gr*128 + k];
      float4 f1 = *(const float4*)&x[(size_t)gr*128 + k + 4];
      v[0]=(short)f2bf(f0.x); v[1]=(short)f2bf(f0.y); v[2]=(short)f2bf(f0.z); v[3]=(short)f2bf(f0.w);
      v[4]=(short)f2bf(f1.x); v[5]=(short)f2bf(f1.y); v[6]=(short)f2bf(f1.z); v[7]=(short)f2bf(f1.w);
    }
    *(bf16x8*)&As[r*128 + (k ^ ((r&7)<<3))] = v;
  }
  __syncthreads();

  const int wid = t>>6, lane = t&63;
  const int l16 = lane&15, kg = lane>>4;
  for (int net=0; net<NNETS; ++net){
    const short* Wt = w0t + (size_t)net*HF*HF;
    f32x4 acc[2][8];
    #pragma unroll
    for (int mt=0; mt<2; ++mt)
      #pragma unroll
      for (int nt=0; nt<8; ++nt){ acc[mt][nt][0]=0.f; acc[mt][nt][1]=0.f; acc[mt][nt][2]=0.f; acc[mt][nt][3]=0.f; }
    #pragma unroll
    for (int ks=0; ks<4; ++ks){
      int k0 = ks*32 + kg*8;
      bf16x8 a0, a1;
      { int r = wid*32 + l16;      a0 = *(const bf16x8*)&As[r*128 + (k0 ^ ((r&7)<<3))]; }
      { int r = wid*32 + 16 + l16; a1 = *(const bf16x8*)&As[r*128 + (k0 ^ ((r&7)<<3))]; }
      #pragma unroll
      for (int nt=0; nt<8; ++nt){
        bf16x8 b = *(const bf16x8*)&Wt[(size_t)(nt*16 + l16)*128 + k0];
        acc[0][nt] = __builtin_amdgcn_mfma_f32_16x16x32_bf16(a0, b, acc[0][nt], 0, 0, 0);
        acc[1][nt] = __builtin_amdgcn_mfma_f32_16x16x32_bf16(a1, b, acc[1][nt], 0, 0, 0);
      }
    }
    #pragma unroll
    for (int mt=0; mt<2; ++mt){
      #pragma unroll
      for (int nt=0; nt<8; ++nt){
        #pragma unroll
        for (int j=0; j<4; ++j){
          int row = rowBase + wid*32 + mt*16 + kg*4 + j;
          int col = nt*16 + l16;
          if (row < NNODES){
            float v = fmaxf(acc[mt][nt][j] + b0[net*HF + col], 0.f);
            short bv = (short)f2bf(v);
            h [IDX(row,net) + col] = bv;
            x0[IDX(row,net) + col] = bv;
          }
        }
      }
    }
  }
}

// ---------------- mid GEMM: h = relu((1-beta)*t + beta*(t @ cw)), net = blockIdx.y ----------------
__global__ __launch_bounds__(256) void gemm_mid(
    const short* __restrict__ A, const short* __restrict__ W, const float beta,
    short* __restrict__ outb)
{
  __shared__ short As[128*128];
  const int t = threadIdx.x;
  const int net = blockIdx.y;
  const int rowBase = blockIdx.x * 128;
  const short* Wt = W + (size_t)net*NLAYERS*HF*HF;

  #pragma unroll
  for (int it=0; it<8; ++it){
    int r = it*16 + (t>>4);
    int k = (t&15)*8;
    int gr = rowBase + r;
    bf16x8 v = {0,0,0,0,0,0,0,0};
    if (gr < NNODES) v = *(const bf16x8*)&A[IDX(gr,net) + k];
    *(bf16x8*)&As[r*128 + (k ^ ((r&7)<<3))] = v;
  }
  __syncthreads();

  const int wid = t>>6, lane = t&63;
  const int l16 = lane&15, kg = lane>>4;
  f32x4 acc[2][8];
  #pragma unroll
  for (int mt=0; mt<2; ++mt)
    #pragma unroll
    for (int nt=0; nt<8; ++nt){ acc[mt][nt][0]=0.f; acc[mt][nt][1]=0.f; acc[mt][nt][2]=0.f; acc[mt][nt][3]=0.f; }

  #pragma unroll
  for (int ks=0; ks<4; ++ks){
    int k0 = ks*32 + kg*8;
    bf16x8 a0, a1;
    { int r = wid*32 + l16;      a0 = *(const bf16x8*)&As[r*128 + (k0 ^ ((r&7)<<3))]; }
    { int r = wid*32 + 16 + l16; a1 = *(const bf16x8*)&As[r*128 + (k0 ^ ((r&7)<<3))]; }
    #pragma unroll
    for (int nt=0; nt<8; ++nt){
      bf16x8 b = *(const bf16x8*)&Wt[(size_t)(nt*16 + l16)*128 + k0];
      acc[0][nt] = __builtin_amdgcn_mfma_f32_16x16x32_bf16(a0, b, acc[0][nt], 0, 0, 0);
      acc[1][nt] = __builtin_amdgcn_mfma_f32_16x16x32_bf16(a1, b, acc[1][nt], 0, 0, 0);
    }
  }

  #pragma unroll
  for (int mt=0; mt<2; ++mt){
    #pragma unroll
    for (int nt=0; nt<8; ++nt){
      #pragma unroll
      for (int j=0; j<4; ++j){
        int rl  = wid*32 + mt*16 + kg*4 + j;
        int row = rowBase + rl;
        int col = nt*16 + l16;
        if (row < NNODES){
          float av = bf2f(As[rl*128 + (col ^ ((rl&7)<<3))]);
          float v = fmaxf((1.f-beta)*av + beta*acc[mt][nt][j], 0.f);
          outb[IDX(row,net) + col] = (short)f2bf(v);
        }
      }
    }
  }
}

// ---------------- output GEMM: logits+log_softmax+ensemble mean, all 3 nets in-block ----------------
__global__ __launch_bounds__(256) void gemm_out(
    const short* __restrict__ h, const short* __restrict__ w1t, const float* __restrict__ b1,
    float* __restrict__ out)
{
  __shared__ short As[128*128];
  const int t = threadIdx.x;
  const int rowBase = blockIdx.x * 128;
  const int wid = t>>6, lane = t&63;
  const int l16 = lane&15, kg = lane>>4;

  f32x4 sum[2][7];
  #pragma unroll
  for (int mt=0; mt<2; ++mt)
    #pragma unroll
    for (int nt=0; nt<7; ++nt){ sum[mt][nt][0]=0.f; sum[mt][nt][1]=0.f; sum[mt][nt][2]=0.f; sum[mt][nt][3]=0.f; }

  for (int net=0; net<NNETS; ++net){
    __syncthreads();
    #pragma unroll
    for (int it=0; it<8; ++it){
      int r = it*16 + (t>>4);
      int k = (t&15)*8;
      int gr = rowBase + r;
      bf16x8 v = {0,0,0,0,0,0,0,0};
      if (gr < NNODES) v = *(const bf16x8*)&h[IDX(gr,net) + k];
      *(bf16x8*)&As[r*128 + (k ^ ((r&7)<<3))] = v;
    }
    __syncthreads();

    const short* Wt = w1t + (size_t)net*OUTF*HF;
    f32x4 acc[2][7];
    #pragma unroll
    for (int mt=0; mt<2; ++mt)
      #pragma unroll
      for (int nt=0; nt<7; ++nt){ acc[mt][nt][0]=0.f; acc[mt][nt][1]=0.f; acc[mt][nt][2]=0.f; acc[mt][nt][3]=0.f; }
    #pragma unroll
    for (int ks=0; ks<4; ++ks){
      int k0 = ks*32 + kg*8;
      bf16x8 a0, a1;
      { int r = wid*32 + l16;      a0 = *(const bf16x8*)&As[r*128 + (k0 ^ ((r&7)<<3))]; }
      { int r = wid*32 + 16 + l16; a1 = *(const bf16x8*)&As[r*128 + (k0 ^ ((r&7)<<3))]; }
      #pragma unroll
      for (int nt=0; nt<7; ++nt){
        bf16x8 b = *(const bf16x8*)&Wt[(size_t)(nt*16 + l16)*128 + k0];
        acc[0][nt] = __builtin_amdgcn_mfma_f32_16x16x32_bf16(a0, b, acc[0][nt], 0, 0, 0);
        acc[1][nt] = __builtin_amdgcn_mfma_f32_16x16x32_bf16(a1, b, acc[1][nt], 0, 0, 0);
      }
    }
    #pragma unroll
    for (int mt=0; mt<2; ++mt)
      #pragma unroll
      for (int nt=0; nt<7; ++nt){
        float b = b1[net*OUTF + nt*16 + l16];
        #pragma unroll
        for (int j=0; j<4; ++j) acc[mt][nt][j] += b;
      }
    #pragma unroll
    for (int mt=0; mt<2; ++mt){
      #pragma unroll
      for (int j=0; j<4; ++j){
        float m = -3.4e38f;
        #pragma unroll
        for (int nt=0; nt<7; ++nt) m = fmaxf(m, acc[mt][nt][j]);
        #pragma unroll
        for (int k=1; k<16; k<<=1) m = fmaxf(m, __shfl_xor(m, k));
        float e = 0.f;
        #pragma unroll
        for (int nt=0; nt<7; ++nt) e += expf(acc[mt][nt][j] - m);
        #pragma unroll
        for (int k=1; k<16; k<<=1) e += __shfl_xor(e, k);
        float lse = m + logf(e);
        #pragma unroll
        for (int nt=0; nt<7; ++nt) sum[mt][nt][j] += acc[mt][nt][j] - lse;
      }
    }
  }

  #pragma unroll
  for (int mt=0; mt<2; ++mt){
    #pragma unroll
    for (int nt=0; nt<7; ++nt){
      #pragma unroll
      for (int j=0; j<4; ++j){
        int row = rowBase + wid*32 + mt*16 + kg*4 + j;
        if (row < NNODES)
          out[(size_t)row*OUTF + nt*16 + l16] = sum[mt][nt][j] * (1.f/3.f);
      }
    }
  }
}

// ---------------- fused SpMM (all 3 nets, one CSR walk): t = 0.9*(A@h) + 0.1*x0 ----------------
// one wave per node; quarter-wave per edge; 3 net-gathers per edge; unroll x2 -> 6 gathers in flight
__global__ __launch_bounds__(256) void spmm3(
    const int* __restrict__ row_ptr, const u64* __restrict__ csr_pack,
    const short* __restrict__ h, const short* __restrict__ x0,
    short* __restrict__ tout)
{
  int node = blockIdx.x*4 + (threadIdx.x>>6);
  int lane = threadIdx.x & 63;
  int q    = lane >> 4;
  int f8   = (lane & 15) * 8;
  int start = row_ptr[node], end = row_ptr[node+1];
  float acc[3][8] = {{0.f},{0.f},{0.f}};
  int e = start + q;
  for (; e + 4 < end; e += 8){
    u64 p0 = csr_pack[e];
    u64 p1 = csr_pack[e+4];
    int   s0 = (int)(unsigned)p0;
    float w0 = __builtin_bit_cast(float, (unsigned)(p0 >> 32));
    int   s1 = (int)(unsigned)p1;
    float w1 = __builtin_bit_cast(float, (unsigned)(p1 >> 32));
    const short* r0 = &h[(size_t)s0*(NNETS*128) + f8];
    const short* r1 = &h[(size_t)s1*(NNETS*128) + f8];
    bf16x8 a0 = *(const bf16x8*)(r0);
    bf16x8 a1 = *(const bf16x8*)(r0 + 128);
    bf16x8 a2 = *(const bf16x8*)(r0 + 256);
    bf16x8 c0 = *(const bf16x8*)(r1);
    bf16x8 c1 = *(const bf16x8*)(r1 + 128);
    bf16x8 c2 = *(const bf16x8*)(r1 + 256);
    #pragma unroll
    for (int j=0;j<8;++j){
      acc[0][j] += w0 * bf2f(a0[j]) + w1 * bf2f(c0[j]);
      acc[1][j] += w0 * bf2f(a1[j]) + w1 * bf2f(c1[j]);
      acc[2][j] += w0 * bf2f(a2[j]) + w1 * bf2f(c2[j]);
    }
  }
  if (e < end){
    u64 p0 = csr_pack[e];
    int   s0 = (int)(unsigned)p0;
    float w0 = __builtin_bit_cast(float, (unsigned)(p0 >> 32));
    const short* r0 = &h[(size_t)s0*(NNETS*128) + f8];
    bf16x8 a0 = *(const bf16x8*)(r0);
    bf16x8 a1 = *(const bf16x8*)(r0 + 128);
    bf16x8 a2 = *(const bf16x8*)(r0 + 256);
    #pragma unroll
    for (int j=0;j<8;++j){
      acc[0][j] += w0 * bf2f(a0[j]);
      acc[1][j] += w0 * bf2f(a1[j]);
      acc[2][j] += w0 * bf2f(a2[j]);
    }
  }
  #pragma unroll
  for (int n=0;n<3;++n)
    #pragma unroll
    for (int j=0;j<8;++j){
      acc[n][j] += __shfl_xor(acc[n][j], 16);
      acc[n][j] += __shfl_xor(acc[n][j], 32);
    }
  if (q < 3){
    size_t base = (size_t)node*(NNETS*128) + q*128 + f8;
    bf16x8 xv = *(const bf16x8*)&x0[base];
    u16x8 o;
    #pragma unroll
    for (int j=0;j<8;++j) o[j] = f2bf(0.9f*acc[q][j] + 0.1f*bf2f(xv[j]));
    *(u16x8*)&tout[base] = o;
  }
}

extern "C" void kernel_launch(void* const* d_in, const int* in_sizes, int n_in,
                              void* d_out, int out_size, void* d_ws, size_t ws_size,
                              hipStream_t stream){
  const float* x  = (const float*)d_in[0];
  const int*   ei = (const int*)d_in[1];
  const float* ew = (const float*)d_in[2];
  const float* w0 = (const float*)d_in[3];
  const float* b0 = (const float*)d_in[4];
  const float* w1 = (const float*)d_in[5];
  const float* b1 = (const float*)d_in[6];
  const float* cw = (const float*)d_in[7];
  float* out = (float*)d_out;

  char* ws = (char*)d_ws;
  size_t o = 0;
  auto alloc = [&](size_t b){ size_t r = o; o += (b + 255) & ~(size_t)255; return r; };
  int*   flag     = (int*)(ws + alloc(256));
  int*   counts   = (int*)(ws + alloc((size_t)NNODES*4));
  int*   scanned  = (int*)(ws + alloc((size_t)NNODES*4));
  int*   cursor   = (int*)(ws + alloc((size_t)NNODES*4));
  int*   row_ptr  = (int*)(ws + alloc((size_t)(NNODES+1)*4));
  int*   partials = (int*)(ws + alloc(512*4));
  u64*   csr_pack = (u64*)(ws + alloc((size_t)NEDGES*8));
  short* w0t = (short*)(ws + alloc((size_t)NNETS*HF*HF*2));
  short* cwt = (short*)(ws + alloc((size_t)NNETS*NLAYERS*HF*HF*2));
  short* w1t = (short*)(ws + alloc((size_t)NNETS*OUTF*HF*2));
  short* hbuf= (short*)(ws + alloc((size_t)NNODES*NNETS*HF*2));
  short* x0b = (short*)(ws + alloc((size_t)NNODES*NNETS*HF*2));
  short* tb  = (short*)(ws + alloc((size_t)NNODES*NNETS*HF*2));
  (void)ws_size; (void)in_sizes; (void)n_in; (void)out_size;
  // total ws use ~248 MB

  detect_fmt    <<<1,   64,  0, stream>>>((const u64*)ei, flag);
  zero_counts   <<<391, 256, 0, stream>>>(counts);
  hist_kernel   <<<6250,256, 0, stream>>>(ei, flag, counts);
  scan1         <<<391, 256, 0, stream>>>(counts, scanned, partials);
  scan2         <<<1,   512, 0, stream>>>(partials, 391);
  scan3         <<<391, 256, 0, stream>>>(scanned, partials, row_ptr, cursor);
  scatter_kernel<<<6250,256, 0, stream>>>(ei, ew, flag, cursor, csr_pack);

  prep_w<<<1128, 256, 0, stream>>>(w0, cw, w1, w0t, cwt, w1t);

  gemm_in<<<782, 256, 0, stream>>>(x, w0t, b0, hbuf, x0b);
  for (int l=0; l<NLAYERS; ++l){
    float beta = logf(0.5f/(float)(l+1) + 1.0f);
    spmm3<<<25000, 256, 0, stream>>>(row_ptr, csr_pack, hbuf, x0b, tb);
    gemm_mid<<<dim3(782,3), 256, 0, stream>>>(tb, cwt + (size_t)l*HF*HF, beta, hbuf);
  }
  gemm_out<<<782, 256, 0, stream>>>(hbuf, w1t, b1, out);
}